// Round 1
// baseline (1028.005 us; speedup 1.0000x reference)
//
#include <hip/hip_runtime.h>

// GNN scatter-add: h[v] = sum_{(u,v) in E} feat[u]
// feat: [N=100000, 64] f32, src/dst: [E=1200000] int32 (harness downcasts int64)
// out: [N, 64] f32
//
// Layout: 16 lanes per edge; lane p loads float4 p of feat[src[e]] (coalesced
// 256B per edge) and does 4 hardware f32 atomics onto out[dst[e]].

#define LANES_PER_EDGE 16

__global__ void gnn_scatter_add_kernel(const float* __restrict__ feat,
                                       const int* __restrict__ src,
                                       const int* __restrict__ dst,
                                       float* __restrict__ out,
                                       int E) {
    const int total = E * LANES_PER_EDGE;  // 19.2M, fits int
    int idx = blockIdx.x * blockDim.x + threadIdx.x;
    const int stride = gridDim.x * blockDim.x;
    for (int i = idx; i < total; i += stride) {
        const int e    = i >> 4;
        const int part = i & (LANES_PER_EDGE - 1);
        const int s = src[e];
        const int d = dst[e];
        const float4 v =
            *reinterpret_cast<const float4*>(feat + (size_t)s * 64 + part * 4);
        float* o = out + (size_t)d * 64 + part * 4;
        // unsafeAtomicAdd emits global_atomic_add_f32 (no CAS loop).
        unsafeAtomicAdd(o + 0, v.x);
        unsafeAtomicAdd(o + 1, v.y);
        unsafeAtomicAdd(o + 2, v.z);
        unsafeAtomicAdd(o + 3, v.w);
    }
}

extern "C" void kernel_launch(void* const* d_in, const int* in_sizes, int n_in,
                              void* d_out, int out_size, void* d_ws, size_t ws_size,
                              hipStream_t stream) {
    const float* feat = (const float*)d_in[0];
    const int*   src  = (const int*)d_in[1];
    const int*   dst  = (const int*)d_in[2];
    float*       out  = (float*)d_out;
    const int E = in_sizes[1];

    // Harness poisons d_out once (0xAA) and never re-poisons between replays:
    // zero it every call.
    hipMemsetAsync(out, 0, (size_t)out_size * sizeof(float), stream);

    const int block = 256;
    const int total = E * LANES_PER_EDGE;
    int grid = (total + block - 1) / block;
    if (grid > 4096) grid = 4096;  // grid-stride; ~2x resident-wave oversubscribe
    gnn_scatter_add_kernel<<<grid, block, 0, stream>>>(feat, src, dst, out, E);
}

// Round 2
// 449.756 us; speedup vs baseline: 2.2857x; 2.2857x over previous
//
#include <hip/hip_runtime.h>

// h[v] = sum_{(u,v) in E} feat[u], feat: [N=100000,64] f32, E=1.2M.
// Strategy: counting sort by dst (CSR) -> per-node wave accumulation.
// No fp32 atomics; only 2.4M int atomics on L2-resident counters.

#define N_SCAN_THREADS 1024

__global__ void hist_kernel(const int* __restrict__ dst, int* __restrict__ cnt, int E) {
    int i = blockIdx.x * blockDim.x + threadIdx.x;
    int stride = gridDim.x * blockDim.x;
    for (; i < E; i += stride) atomicAdd(&cnt[dst[i]], 1);
}

// Single-block in-place exclusive scan of cnt[0..N) -> rowptr, plus cursor copy.
__global__ void scan_kernel(int* __restrict__ rowptr, int* __restrict__ cursor, int N) {
    __shared__ int sums[N_SCAN_THREADS];
    const int t = threadIdx.x;
    const int chunk = (N + N_SCAN_THREADS - 1) / N_SCAN_THREADS;
    const int b = t * chunk;
    const int e = min(N, b + chunk);
    int s = 0;
    for (int i = b; i < e; ++i) s += rowptr[i];
    sums[t] = s;
    __syncthreads();
    // Hillis-Steele inclusive scan over per-thread sums.
    for (int off = 1; off < N_SCAN_THREADS; off <<= 1) {
        int v = (t >= off) ? sums[t - off] : 0;
        __syncthreads();
        sums[t] += v;
        __syncthreads();
    }
    int run = (t == 0) ? 0 : sums[t - 1];
    for (int i = b; i < e; ++i) {
        int c = rowptr[i];
        rowptr[i] = run;
        cursor[i] = run;
        run += c;
    }
    if (t == N_SCAN_THREADS - 1) rowptr[N] = sums[N_SCAN_THREADS - 1];
}

__global__ void scatter_kernel(const int* __restrict__ src, const int* __restrict__ dst,
                               int* __restrict__ cursor, int* __restrict__ sorted_src, int E) {
    int i = blockIdx.x * blockDim.x + threadIdx.x;
    int stride = gridDim.x * blockDim.x;
    for (; i < E; i += stride) {
        int d = dst[i];
        int pos = atomicAdd(&cursor[d], 1);
        sorted_src[pos] = src[i];
    }
}

// One wave per node; lane = feature column. Each edge: coalesced 256B gather.
__global__ void gather_sum_kernel(const float* __restrict__ feat,
                                  const int* __restrict__ rowptr,
                                  const int* __restrict__ sorted_src,
                                  float* __restrict__ out, int N) {
    const int wave = (blockIdx.x * blockDim.x + threadIdx.x) >> 6;
    const int lane = threadIdx.x & 63;
    if (wave >= N) return;
    const int beg = rowptr[wave];
    const int end = rowptr[wave + 1];
    float acc = 0.0f;
    for (int k = beg; k < end; k += 64) {
        const int m = min(64, end - k);
        const int id = (lane < m) ? sorted_src[k + lane] : 0;
        for (int j = 0; j < m; ++j) {
            const int s = __shfl(id, j);
            acc += feat[(size_t)s * 64 + lane];
        }
    }
    out[(size_t)wave * 64 + lane] = acc;
}

// Fallback (ws too small): direct fp32-atomic scatter-add.
__global__ void atomic_fallback_kernel(const float* __restrict__ feat,
                                       const int* __restrict__ src,
                                       const int* __restrict__ dst,
                                       float* __restrict__ out, int E) {
    const int total = E * 16;
    int idx = blockIdx.x * blockDim.x + threadIdx.x;
    const int stride = gridDim.x * blockDim.x;
    for (int i = idx; i < total; i += stride) {
        const int e = i >> 4;
        const int part = i & 15;
        const float4 v = *reinterpret_cast<const float4*>(feat + (size_t)src[e] * 64 + part * 4);
        float* o = out + (size_t)dst[e] * 64 + part * 4;
        unsafeAtomicAdd(o + 0, v.x);
        unsafeAtomicAdd(o + 1, v.y);
        unsafeAtomicAdd(o + 2, v.z);
        unsafeAtomicAdd(o + 3, v.w);
    }
}

extern "C" void kernel_launch(void* const* d_in, const int* in_sizes, int n_in,
                              void* d_out, int out_size, void* d_ws, size_t ws_size,
                              hipStream_t stream) {
    const float* feat = (const float*)d_in[0];
    const int*   src  = (const int*)d_in[1];
    const int*   dst  = (const int*)d_in[2];
    float*       out  = (float*)d_out;
    const int E = in_sizes[1];
    const int N = out_size / 64;  // 100000

    const size_t needed = ((size_t)(N + 1) + N + E) * sizeof(int);
    if (ws_size < needed) {
        hipMemsetAsync(out, 0, (size_t)out_size * sizeof(float), stream);
        int grid = (E * 16 + 255) / 256;
        if (grid > 4096) grid = 4096;
        atomic_fallback_kernel<<<grid, 256, 0, stream>>>(feat, src, dst, out, E);
        return;
    }

    int* rowptr = (int*)d_ws;           // N+1
    int* cursor = rowptr + (N + 1);     // N
    int* sorted = cursor + N;           // E

    hipMemsetAsync(rowptr, 0, (size_t)(N + 1) * sizeof(int), stream);

    int gridE = (E + 255) / 256;
    if (gridE > 2048) gridE = 2048;
    hist_kernel<<<gridE, 256, 0, stream>>>(dst, rowptr, E);
    scan_kernel<<<1, N_SCAN_THREADS, 0, stream>>>(rowptr, cursor, N);
    scatter_kernel<<<gridE, 256, 0, stream>>>(src, dst, cursor, sorted, E);

    const int gridN = (N * 64 + 255) / 256;  // one wave per node
    gather_sum_kernel<<<gridN, 256, 0, stream>>>(feat, rowptr, sorted, out, N);
}

// Round 3
// 202.566 us; speedup vs baseline: 5.0749x; 2.2203x over previous
//
#include <hip/hip_runtime.h>

// h[v] = sum_{(u,v) in E} feat[u], feat: [N=100000,64] f32, E=1.2M.
// Counting sort by dst (CSR) -> per-node wave accumulation. No fp32 atomics.
// Round 3: parallel 3-pass scan (was 234us single-block), 4-edges-per-wave gather.

#define CHUNK 1024
#define SCAN_BLOCK 256  // threads per scan block, 4 elems each

__global__ void hist_kernel(const int* __restrict__ dst, int* __restrict__ cnt, int E) {
    int i = blockIdx.x * blockDim.x + threadIdx.x;
    int stride = gridDim.x * blockDim.x;
    for (; i < E; i += stride) atomicAdd(&cnt[dst[i]], 1);
}

// Pass 1: per-block sums of cnt chunks.
__global__ void partial_sum_kernel(const int* __restrict__ cnt, int* __restrict__ bsum, int N) {
    __shared__ int red[SCAN_BLOCK];
    const int b = blockIdx.x;
    const int base = b * CHUNK + threadIdx.x * 4;
    int s = 0;
    if (base + 3 < N) {
        int4 v = *reinterpret_cast<const int4*>(cnt + base);
        s = v.x + v.y + v.z + v.w;
    } else {
        for (int i = 0; i < 4; ++i) if (base + i < N) s += cnt[base + i];
    }
    red[threadIdx.x] = s;
    __syncthreads();
    for (int off = SCAN_BLOCK / 2; off > 0; off >>= 1) {
        if (threadIdx.x < off) red[threadIdx.x] += red[threadIdx.x + off];
        __syncthreads();
    }
    if (threadIdx.x == 0) bsum[b] = red[0];
}

// Pass 2: single small block, exclusive scan of B block sums (B <= 1024).
__global__ void scan_bsum_kernel(int* __restrict__ bsum, int B,
                                 int* __restrict__ rowptr, int N, int E) {
    __shared__ int sh[1024];
    const int t = threadIdx.x;
    const int v = (t < B) ? bsum[t] : 0;
    sh[t] = v;
    __syncthreads();
    for (int off = 1; off < 1024; off <<= 1) {
        int u = (t >= off) ? sh[t - off] : 0;
        __syncthreads();
        sh[t] += u;
        __syncthreads();
    }
    if (t < B) bsum[t] = sh[t] - v;  // exclusive
    if (t == 0) rowptr[N] = E;
}

// Pass 3: per-block local exclusive scan + block offset -> rowptr, cursor.
__global__ void scan_final_kernel(const int* __restrict__ cnt, const int* __restrict__ bsum,
                                  int* __restrict__ rowptr, int* __restrict__ cursor, int N) {
    __shared__ int sh[SCAN_BLOCK];
    const int b = blockIdx.x;
    const int t = threadIdx.x;
    const int base = b * CHUNK + t * 4;
    int v0 = 0, v1 = 0, v2 = 0, v3 = 0;
    const bool fast = (base + 3 < N);
    if (fast) {
        int4 q = *reinterpret_cast<const int4*>(cnt + base);
        v0 = q.x; v1 = q.y; v2 = q.z; v3 = q.w;
    } else {
        if (base + 0 < N) v0 = cnt[base + 0];
        if (base + 1 < N) v1 = cnt[base + 1];
        if (base + 2 < N) v2 = cnt[base + 2];
        if (base + 3 < N) v3 = cnt[base + 3];
    }
    const int s = v0 + v1 + v2 + v3;
    sh[t] = s;
    __syncthreads();
    for (int off = 1; off < SCAN_BLOCK; off <<= 1) {
        int u = (t >= off) ? sh[t - off] : 0;
        __syncthreads();
        sh[t] += u;
        __syncthreads();
    }
    int run = bsum[b] + sh[t] - s;  // exclusive prefix of this thread's first elem
    if (fast) {
        int4 w;
        w.x = run;
        w.y = run + v0;
        w.z = run + v0 + v1;
        w.w = run + v0 + v1 + v2;
        *reinterpret_cast<int4*>(rowptr + base) = w;
        *reinterpret_cast<int4*>(cursor + base) = w;
    } else {
        int r = run;
        if (base + 0 < N) { rowptr[base + 0] = r; cursor[base + 0] = r; r += v0; }
        if (base + 1 < N) { rowptr[base + 1] = r; cursor[base + 1] = r; r += v1; }
        if (base + 2 < N) { rowptr[base + 2] = r; cursor[base + 2] = r; r += v2; }
        if (base + 3 < N) { rowptr[base + 3] = r; cursor[base + 3] = r; r += v3; }
    }
}

__global__ void scatter_kernel(const int* __restrict__ src, const int* __restrict__ dst,
                               int* __restrict__ cursor, int* __restrict__ sorted_src, int E) {
    int i = blockIdx.x * blockDim.x + threadIdx.x;
    int stride = gridDim.x * blockDim.x;
    for (; i < E; i += stride) {
        int d = dst[i];
        int pos = atomicAdd(&cursor[d], 1);
        sorted_src[pos] = src[i];
    }
}

// One wave per node. Layout: 4 edge-slots x 16 lanes (float4 each).
// 4 edges gathered per iteration (independent loads), cross-slot shfl reduce,
// one coalesced float4 row store from slot 0.
__global__ void gather_sum_kernel(const float* __restrict__ feat,
                                  const int* __restrict__ rowptr,
                                  const int* __restrict__ sorted_src,
                                  float* __restrict__ out, int N) {
    const int wave = (blockIdx.x * blockDim.x + threadIdx.x) >> 6;
    const int lane = threadIdx.x & 63;
    if (wave >= N) return;
    const int beg = rowptr[wave];
    const int end = rowptr[wave + 1];
    const int slot = lane >> 4;   // 0..3
    const int part = lane & 15;   // float4 column group
    float4 acc = make_float4(0.f, 0.f, 0.f, 0.f);
    for (int k = beg + slot; k < end; k += 4) {
        const int s = sorted_src[k];
        const float4 v = *reinterpret_cast<const float4*>(feat + (size_t)s * 64 + part * 4);
        acc.x += v.x; acc.y += v.y; acc.z += v.z; acc.w += v.w;
    }
    acc.x += __shfl_xor(acc.x, 16); acc.y += __shfl_xor(acc.y, 16);
    acc.z += __shfl_xor(acc.z, 16); acc.w += __shfl_xor(acc.w, 16);
    acc.x += __shfl_xor(acc.x, 32); acc.y += __shfl_xor(acc.y, 32);
    acc.z += __shfl_xor(acc.z, 32); acc.w += __shfl_xor(acc.w, 32);
    if (slot == 0)
        *reinterpret_cast<float4*>(out + (size_t)wave * 64 + part * 4) = acc;
}

// Fallback (ws too small): direct fp32-atomic scatter-add.
__global__ void atomic_fallback_kernel(const float* __restrict__ feat,
                                       const int* __restrict__ src,
                                       const int* __restrict__ dst,
                                       float* __restrict__ out, int E) {
    const int total = E * 16;
    int idx = blockIdx.x * blockDim.x + threadIdx.x;
    const int stride = gridDim.x * blockDim.x;
    for (int i = idx; i < total; i += stride) {
        const int e = i >> 4;
        const int part = i & 15;
        const float4 v = *reinterpret_cast<const float4*>(feat + (size_t)src[e] * 64 + part * 4);
        float* o = out + (size_t)dst[e] * 64 + part * 4;
        unsafeAtomicAdd(o + 0, v.x);
        unsafeAtomicAdd(o + 1, v.y);
        unsafeAtomicAdd(o + 2, v.z);
        unsafeAtomicAdd(o + 3, v.w);
    }
}

extern "C" void kernel_launch(void* const* d_in, const int* in_sizes, int n_in,
                              void* d_out, int out_size, void* d_ws, size_t ws_size,
                              hipStream_t stream) {
    const float* feat = (const float*)d_in[0];
    const int*   src  = (const int*)d_in[1];
    const int*   dst  = (const int*)d_in[2];
    float*       out  = (float*)d_out;
    const int E = in_sizes[1];
    const int N = out_size / 64;  // 100000
    const int B = (N + CHUNK - 1) / CHUNK;  // 98 scan blocks (<=1024 supported)

    const size_t needed = ((size_t)(N + 1) + N + N + 1024 + E) * sizeof(int);
    if (ws_size < needed || B > 1024) {
        hipMemsetAsync(out, 0, (size_t)out_size * sizeof(float), stream);
        int grid = (E * 16 + 255) / 256;
        if (grid > 4096) grid = 4096;
        atomic_fallback_kernel<<<grid, 256, 0, stream>>>(feat, src, dst, out, E);
        return;
    }

    int* rowptr = (int*)d_ws;            // N+1
    int* cursor = rowptr + (N + 1);      // N
    int* cnt    = cursor + N;            // N
    int* bsum   = cnt + N;               // 1024
    int* sorted = bsum + 1024;           // E

    hipMemsetAsync(cnt, 0, (size_t)N * sizeof(int), stream);

    int gridE = (E + 255) / 256;
    if (gridE > 2048) gridE = 2048;
    hist_kernel<<<gridE, 256, 0, stream>>>(dst, cnt, E);
    partial_sum_kernel<<<B, SCAN_BLOCK, 0, stream>>>(cnt, bsum, N);
    scan_bsum_kernel<<<1, 1024, 0, stream>>>(bsum, B, rowptr, N, E);
    scan_final_kernel<<<B, SCAN_BLOCK, 0, stream>>>(cnt, bsum, rowptr, cursor, N);
    scatter_kernel<<<gridE, 256, 0, stream>>>(src, dst, cursor, sorted, E);

    const int gridN = (N * 64 + 255) / 256;  // one wave per node
    gather_sum_kernel<<<gridN, 256, 0, stream>>>(feat, rowptr, sorted, out, N);
}